// Round 1
// baseline (1231.452 us; speedup 1.0000x reference)
//
#include <hip/hip_runtime.h>

// ---------------------------------------------------------------------------
// GCN pipeline, fp32 throughout (threshold 2.7e-4 rules out bf16 MFMA).
//  A = x@W1 ; B = A*dinv^2 + b1 ; B += scatter(A[src]*norm) ;
//  A = relu(B)@W2 ; B = A*dinv^2 + b2 ; B += scatter ;
//  pooled = segment_mean(relu(B), batch) ; out = relu(pooled@Wfc1+bfc1)@Wfc2+bfc2
// ---------------------------------------------------------------------------

__global__ void deg_kernel(const int* __restrict__ dst, float* deg, int E) {
    int e = blockIdx.x * blockDim.x + threadIdx.x;
    if (e < E) atomicAdd(&deg[dst[e]], 1.0f);
}

__global__ void dinv_kernel(float* deg, int N) {
    int n = blockIdx.x * blockDim.x + threadIdx.x;
    if (n < N) deg[n] = 1.0f / sqrtf(deg[n] + 1.0f);  // correctly-rounded path
}

// C[M,128] = act(X)[M,128] @ W[128,128].  BM=64, BK=32, 4x8 micro-tile.
template <bool RELU_IN>
__global__ __launch_bounds__(256) void gemm128(const float* __restrict__ X,
                                               const float* __restrict__ W,
                                               float* __restrict__ OUT, int M) {
    const int BM = 64, BK = 32;
    __shared__ float Xs[BM][BK + 4];   // +4 pad keeps float4 writes 16B-aligned
    __shared__ float Ws[BK][128];
    int tid = threadIdx.x;
    int m0 = blockIdx.x * BM;
    int tx = tid & 15;   // col group: c = tx*8
    int ty = tid >> 4;   // row group: r = ty*4

    float acc[4][8];
#pragma unroll
    for (int i = 0; i < 4; i++)
#pragma unroll
        for (int j = 0; j < 8; j++) acc[i][j] = 0.f;

    for (int kk = 0; kk < 128; kk += BK) {
        // X tile: 64 rows x 32 k = 512 float4, 2 per thread
#pragma unroll
        for (int t = 0; t < 2; t++) {
            int idx = tid + t * 256;      // 0..511
            int m = idx >> 3;             // row in tile
            int kq = idx & 7;             // float4 index along k
            int row = m0 + m;
            float4 v = make_float4(0.f, 0.f, 0.f, 0.f);
            if (row < M) v = *(const float4*)(X + (size_t)row * 128 + kk + kq * 4);
            if (RELU_IN) {
                v.x = fmaxf(v.x, 0.f); v.y = fmaxf(v.y, 0.f);
                v.z = fmaxf(v.z, 0.f); v.w = fmaxf(v.w, 0.f);
            }
            *(float4*)&Xs[m][kq * 4] = v;
        }
        // W tile: 32 k x 128 = 1024 float4, 4 per thread
#pragma unroll
        for (int t = 0; t < 4; t++) {
            int idx = tid + t * 256;      // 0..1023
            int k = idx >> 5;
            int q = idx & 31;
            float4 v = *(const float4*)(W + (size_t)(kk + k) * 128 + q * 4);
            *(float4*)&Ws[k][q * 4] = v;
        }
        __syncthreads();
#pragma unroll
        for (int k = 0; k < BK; k++) {
            float xr[4];
#pragma unroll
            for (int i = 0; i < 4; i++) xr[i] = Xs[ty * 4 + i][k];
            float4 w0 = *(const float4*)&Ws[k][tx * 8];
            float4 w1 = *(const float4*)&Ws[k][tx * 8 + 4];
            float wv[8] = {w0.x, w0.y, w0.z, w0.w, w1.x, w1.y, w1.z, w1.w};
#pragma unroll
            for (int i = 0; i < 4; i++)
#pragma unroll
                for (int j = 0; j < 8; j++)
                    acc[i][j] = fmaf(xr[i], wv[j], acc[i][j]);
        }
        __syncthreads();
    }
#pragma unroll
    for (int i = 0; i < 4; i++) {
        int row = m0 + ty * 4 + i;
        if (row < M) {
            float4 o0 = make_float4(acc[i][0], acc[i][1], acc[i][2], acc[i][3]);
            float4 o1 = make_float4(acc[i][4], acc[i][5], acc[i][6], acc[i][7]);
            *(float4*)(OUT + (size_t)row * 128 + tx * 8) = o0;
            *(float4*)(OUT + (size_t)row * 128 + tx * 8 + 4) = o1;
        }
    }
}

// B[n,c] = h[n,c]*dinv[n]^2 + bias[c]   (self-loop term + bias, full overwrite)
__global__ void init_self(const float* __restrict__ h, const float* __restrict__ dinv,
                          const float* __restrict__ bias, float* __restrict__ B, int N) {
    int idx = blockIdx.x * blockDim.x + threadIdx.x;
    if (idx < N * 128) {
        int n = idx >> 7, c = idx & 127;
        float di = dinv[n];
        B[idx] = h[idx] * di * di + bias[c];
    }
}

// One wave per edge; lane covers 2 feature channels (float2 gather, 2 atomics).
__global__ __launch_bounds__(256) void scatter_edges(const int* __restrict__ src,
                                                     const int* __restrict__ dst,
                                                     const float* __restrict__ dinv,
                                                     const float* __restrict__ h,
                                                     float* __restrict__ B, int E) {
    long long gid = (long long)blockIdx.x * 256 + threadIdx.x;
    int e = (int)(gid >> 6);
    int lane = (int)(gid & 63);
    if (e >= E) return;
    int s = src[e], d = dst[e];
    float norm = dinv[s] * dinv[d];
    float2 hv = *(const float2*)(h + (size_t)s * 128 + lane * 2);
    atomicAdd(&B[(size_t)d * 128 + lane * 2], hv.x * norm);
    atomicAdd(&B[(size_t)d * 128 + lane * 2 + 1], hv.y * norm);
}

// Pool: batch is sorted, so run-length accumulate, atomic only on transitions.
__global__ __launch_bounds__(256) void pool_kernel(const float* __restrict__ B,
                                                   const int* __restrict__ batch,
                                                   float* pooled, float* cnt, int N) {
    int c = threadIdx.x & 127;
    int half = threadIdx.x >> 7;
    int n0 = blockIdx.x * 128;
    float acc = 0.f, cacc = 0.f;
    int curg = -1;
    for (int i = half; i < 128; i += 2) {
        int n = n0 + i;
        if (n >= N) break;
        int g = batch[n];
        float v = fmaxf(B[(size_t)n * 128 + c], 0.f);
        if (g != curg) {
            if (curg >= 0) {
                atomicAdd(&pooled[curg * 128 + c], acc);
                if (c == 0) atomicAdd(&cnt[curg], cacc);
            }
            curg = g; acc = 0.f; cacc = 0.f;
        }
        acc += v; cacc += 1.f;
    }
    if (curg >= 0) {
        atomicAdd(&pooled[curg * 128 + c], acc);
        if (c == 0) atomicAdd(&cnt[curg], cacc);
    }
}

// mean -> FC1(relu) -> FC2, one block.
__global__ __launch_bounds__(256) void head_kernel(const float* __restrict__ pooled,
                                                   const float* __restrict__ cnt,
                                                   const float* __restrict__ Wfc1,
                                                   const float* __restrict__ bfc1,
                                                   const float* __restrict__ Wfc2,
                                                   const float* __restrict__ bfc2,
                                                   float* __restrict__ out) {
    __shared__ float mean[64 * 128];
    __shared__ float fc1[64 * 64];
    int tid = threadIdx.x;
#pragma unroll
    for (int t = 0; t < 32; t++) {
        int idx = tid + t * 256;        // 0..8191
        int g = idx >> 7;
        mean[idx] = pooled[idx] / fmaxf(cnt[g], 1.0f);
    }
    __syncthreads();
    for (int t = 0; t < 16; t++) {
        int idx = tid + t * 256;        // 0..4095
        int g = idx >> 6, oc = idx & 63;
        float s = bfc1[oc];
        for (int k = 0; k < 128; k++) s = fmaf(mean[g * 128 + k], Wfc1[k * 64 + oc], s);
        fc1[idx] = fmaxf(s, 0.f);
    }
    __syncthreads();
    if (tid < 64) {
        float s = bfc2[0];
        for (int k = 0; k < 64; k++) s = fmaf(fc1[tid * 64 + k], Wfc2[k], s);
        out[tid] = s;
    }
}

extern "C" void kernel_launch(void* const* d_in, const int* in_sizes, int n_in,
                              void* d_out, int out_size, void* d_ws, size_t ws_size,
                              hipStream_t stream) {
    const float* x    = (const float*)d_in[0];
    const int*   edge = (const int*)d_in[1];
    const int*   batch= (const int*)d_in[2];
    const float* W1   = (const float*)d_in[3];
    const float* b1   = (const float*)d_in[4];
    const float* W2   = (const float*)d_in[5];
    const float* b2   = (const float*)d_in[6];
    const float* Wfc1 = (const float*)d_in[7];
    const float* bfc1 = (const float*)d_in[8];
    const float* Wfc2 = (const float*)d_in[9];
    const float* bfc2 = (const float*)d_in[10];
    float* out = (float*)d_out;

    int N = in_sizes[0] / 128;
    int E = in_sizes[1] / 2;
    const int* src = edge;
    const int* dst = edge + E;

    char* ws = (char*)d_ws;
    size_t featBytes = (size_t)N * 128 * sizeof(float);
    float* A    = (float*)ws;                       // [N,128]
    float* B    = (float*)(ws + featBytes);         // [N,128]
    float* dinv = (float*)(ws + 2 * featBytes);     // [N] (deg, then in-place 1/sqrt)
    float* pooled = (float*)((char*)dinv + (size_t)N * sizeof(float)); // [64*128]
    float* cnt    = pooled + 64 * 128;              // [64]

    hipMemsetAsync(dinv, 0, (size_t)N * sizeof(float), stream);
    hipMemsetAsync(pooled, 0, (64 * 128 + 64) * sizeof(float), stream);

    deg_kernel<<<(E + 255) / 256, 256, 0, stream>>>(dst, dinv, E);
    dinv_kernel<<<(N + 255) / 256, 256, 0, stream>>>(dinv, N);

    int gblocks = (N + 63) / 64;
    int eblocks = (int)(((long long)E * 64 + 255) / 256);
    int iblocks = (N * 128 + 255) / 256;

    // Layer 1
    gemm128<false><<<gblocks, 256, 0, stream>>>(x, W1, A, N);
    init_self<<<iblocks, 256, 0, stream>>>(A, dinv, b1, B, N);
    scatter_edges<<<eblocks, 256, 0, stream>>>(src, dst, dinv, A, B, E);

    // Layer 2 (relu fused into GEMM input read)
    gemm128<true><<<gblocks, 256, 0, stream>>>(B, W2, A, N);
    init_self<<<iblocks, 256, 0, stream>>>(A, dinv, b2, B, N);
    scatter_edges<<<eblocks, 256, 0, stream>>>(src, dst, dinv, A, B, E);

    // Pool (relu fused) + head
    pool_kernel<<<(N + 127) / 128, 256, 0, stream>>>(B, batch, pooled, cnt, N);
    head_kernel<<<1, 256, 0, stream>>>(pooled, cnt, Wfc1, bfc1, Wfc2, bfc2, out);
}

// Round 2
// 368.126 us; speedup vs baseline: 3.3452x; 3.3452x over previous
//
#include <hip/hip_runtime.h>

// ---------------------------------------------------------------------------
// GCN pipeline, fp32. Round 2: pull-based CSR aggregation (no fp32 atomics in
// the hot path). CSR rebuilt every call (workspace is re-poisoned).
//  build: hist(dst) -> scan -> reorder ;
//  layer: A = act(X)@W ; B[n] = sum_{e->n} A[src]*norm + A[n]*dinv^2 + bias
// ---------------------------------------------------------------------------

__global__ void hist_kernel(const int* __restrict__ dst, int* __restrict__ count, int E) {
    int e = blockIdx.x * blockDim.x + threadIdx.x;
    if (e < E) atomicAdd(&count[dst[e]], 1);
}

// pass 1: per-block inclusive scan of count -> tmp; block sums -> bsum
__global__ __launch_bounds__(256) void scan1_kernel(const int* __restrict__ count,
                                                    int* __restrict__ tmp,
                                                    int* __restrict__ bsum, int N) {
    __shared__ int s[256];
    int tid = threadIdx.x;
    int i = blockIdx.x * 256 + tid;
    int v = (i < N) ? count[i] : 0;
    s[tid] = v;
    __syncthreads();
#pragma unroll
    for (int off = 1; off < 256; off <<= 1) {
        int t = (tid >= off) ? s[tid - off] : 0;
        __syncthreads();
        s[tid] += t;
        __syncthreads();
    }
    if (i < N) tmp[i] = s[tid];
    if (tid == 255) bsum[blockIdx.x] = s[255];
}

// pass 2: exclusive scan of block sums (single block; nb <= 256)
__global__ __launch_bounds__(256) void scan2_kernel(const int* __restrict__ bsum,
                                                    int* __restrict__ boff, int nb) {
    __shared__ int s[256];
    int tid = threadIdx.x;
    int v = (tid < nb) ? bsum[tid] : 0;
    s[tid] = v;
    __syncthreads();
#pragma unroll
    for (int off = 1; off < 256; off <<= 1) {
        int t = (tid >= off) ? s[tid - off] : 0;
        __syncthreads();
        s[tid] += t;
        __syncthreads();
    }
    if (tid < nb) boff[tid] = s[tid] - v;   // exclusive
}

// pass 3: rowptr (exclusive), cursor copy, dinv
__global__ void finalize_kernel(const int* __restrict__ count, const int* __restrict__ tmp,
                                const int* __restrict__ boff, int* __restrict__ rowptr,
                                int* __restrict__ cursor, float* __restrict__ dinv, int N) {
    int i = blockIdx.x * blockDim.x + threadIdx.x;
    if (i > N) return;
    int ex = (i == 0) ? 0 : tmp[i - 1] + boff[(i - 1) >> 8];
    rowptr[i] = ex;
    if (i < N) {
        cursor[i] = ex;
        dinv[i] = 1.0f / sqrtf((float)count[i] + 1.0f);
    }
}

__global__ void reorder_kernel(const int* __restrict__ src, const int* __restrict__ dst,
                               int* __restrict__ cursor, int* __restrict__ esrc, int E) {
    int e = blockIdx.x * blockDim.x + threadIdx.x;
    if (e < E) {
        int pos = atomicAdd(&cursor[dst[e]], 1);
        esrc[pos] = src[e];
    }
}

// One wave per node: pull all in-edges, fused self-loop + bias. No atomics.
__global__ __launch_bounds__(256) void gather_csr(const float* __restrict__ h,
                                                  const float* __restrict__ dinv,
                                                  const float* __restrict__ bias,
                                                  const int* __restrict__ rowptr,
                                                  const int* __restrict__ esrc,
                                                  float* __restrict__ B, int N) {
    int n = blockIdx.x * 4 + (threadIdx.x >> 6);
    int lane = threadIdx.x & 63;
    if (n >= N) return;
    int beg = rowptr[n], end = rowptr[n + 1];
    float din = dinv[n];
    float2 hv = *(const float2*)(h + (size_t)n * 128 + lane * 2);
    float2 acc;
    acc.x = hv.x * din * din;
    acc.y = hv.y * din * din;
    for (int j0 = beg; j0 < end; j0 += 64) {
        int m = end - j0; if (m > 64) m = 64;
        int sl = 0; float nl = 0.f;
        if (j0 + lane < end) {
            sl = esrc[j0 + lane];
            nl = dinv[sl] * din;
        }
        for (int t = 0; t < m; t++) {
            int s = __shfl(sl, t, 64);
            float nrm = __shfl(nl, t, 64);
            float2 hs = *(const float2*)(h + (size_t)s * 128 + lane * 2);
            acc.x = fmaf(hs.x, nrm, acc.x);
            acc.y = fmaf(hs.y, nrm, acc.y);
        }
    }
    float2 o;
    o.x = acc.x + bias[lane * 2];
    o.y = acc.y + bias[lane * 2 + 1];
    *(float2*)(B + (size_t)n * 128 + lane * 2) = o;
}

// C[M,128] = act(X)[M,128] @ W[128,128].  BM=64, BK=32, 4x8 micro-tile.
template <bool RELU_IN>
__global__ __launch_bounds__(256) void gemm128(const float* __restrict__ X,
                                               const float* __restrict__ W,
                                               float* __restrict__ OUT, int M) {
    const int BM = 64, BK = 32;
    __shared__ float Xs[BM][BK + 4];
    __shared__ float Ws[BK][128];
    int tid = threadIdx.x;
    int m0 = blockIdx.x * BM;
    int tx = tid & 15;
    int ty = tid >> 4;

    float acc[4][8];
#pragma unroll
    for (int i = 0; i < 4; i++)
#pragma unroll
        for (int j = 0; j < 8; j++) acc[i][j] = 0.f;

    for (int kk = 0; kk < 128; kk += BK) {
#pragma unroll
        for (int t = 0; t < 2; t++) {
            int idx = tid + t * 256;
            int m = idx >> 3;
            int kq = idx & 7;
            int row = m0 + m;
            float4 v = make_float4(0.f, 0.f, 0.f, 0.f);
            if (row < M) v = *(const float4*)(X + (size_t)row * 128 + kk + kq * 4);
            if (RELU_IN) {
                v.x = fmaxf(v.x, 0.f); v.y = fmaxf(v.y, 0.f);
                v.z = fmaxf(v.z, 0.f); v.w = fmaxf(v.w, 0.f);
            }
            *(float4*)&Xs[m][kq * 4] = v;
        }
#pragma unroll
        for (int t = 0; t < 4; t++) {
            int idx = tid + t * 256;
            int k = idx >> 5;
            int q = idx & 31;
            float4 v = *(const float4*)(W + (size_t)(kk + k) * 128 + q * 4);
            *(float4*)&Ws[k][q * 4] = v;
        }
        __syncthreads();
#pragma unroll
        for (int k = 0; k < BK; k++) {
            float xr[4];
#pragma unroll
            for (int i = 0; i < 4; i++) xr[i] = Xs[ty * 4 + i][k];
            float4 w0 = *(const float4*)&Ws[k][tx * 8];
            float4 w1 = *(const float4*)&Ws[k][tx * 8 + 4];
            float wv[8] = {w0.x, w0.y, w0.z, w0.w, w1.x, w1.y, w1.z, w1.w};
#pragma unroll
            for (int i = 0; i < 4; i++)
#pragma unroll
                for (int j = 0; j < 8; j++)
                    acc[i][j] = fmaf(xr[i], wv[j], acc[i][j]);
        }
        __syncthreads();
    }
#pragma unroll
    for (int i = 0; i < 4; i++) {
        int row = m0 + ty * 4 + i;
        if (row < M) {
            float4 o0 = make_float4(acc[i][0], acc[i][1], acc[i][2], acc[i][3]);
            float4 o1 = make_float4(acc[i][4], acc[i][5], acc[i][6], acc[i][7]);
            *(float4*)(OUT + (size_t)row * 128 + tx * 8) = o0;
            *(float4*)(OUT + (size_t)row * 128 + tx * 8 + 4) = o1;
        }
    }
}

// Pool: batch sorted -> run-length accumulate, atomics only at transitions.
__global__ __launch_bounds__(256) void pool_kernel(const float* __restrict__ B,
                                                   const int* __restrict__ batch,
                                                   float* pooled, float* cnt, int N) {
    int c = threadIdx.x & 127;
    int half = threadIdx.x >> 7;
    int n0 = blockIdx.x * 128;
    float acc = 0.f, cacc = 0.f;
    int curg = -1;
    for (int i = half; i < 128; i += 2) {
        int n = n0 + i;
        if (n >= N) break;
        int g = batch[n];
        float v = fmaxf(B[(size_t)n * 128 + c], 0.f);
        if (g != curg) {
            if (curg >= 0) {
                atomicAdd(&pooled[curg * 128 + c], acc);
                if (c == 0) atomicAdd(&cnt[curg], cacc);
            }
            curg = g; acc = 0.f; cacc = 0.f;
        }
        acc += v; cacc += 1.f;
    }
    if (curg >= 0) {
        atomicAdd(&pooled[curg * 128 + c], acc);
        if (c == 0) atomicAdd(&cnt[curg], cacc);
    }
}

__global__ __launch_bounds__(256) void head_kernel(const float* __restrict__ pooled,
                                                   const float* __restrict__ cnt,
                                                   const float* __restrict__ Wfc1,
                                                   const float* __restrict__ bfc1,
                                                   const float* __restrict__ Wfc2,
                                                   const float* __restrict__ bfc2,
                                                   float* __restrict__ out) {
    __shared__ float mean[64 * 128];
    __shared__ float fc1[64 * 64];
    int tid = threadIdx.x;
#pragma unroll
    for (int t = 0; t < 32; t++) {
        int idx = tid + t * 256;
        int g = idx >> 7;
        mean[idx] = pooled[idx] / fmaxf(cnt[g], 1.0f);
    }
    __syncthreads();
    for (int t = 0; t < 16; t++) {
        int idx = tid + t * 256;
        int g = idx >> 6, oc = idx & 63;
        float s = bfc1[oc];
        for (int k = 0; k < 128; k++) s = fmaf(mean[g * 128 + k], Wfc1[k * 64 + oc], s);
        fc1[idx] = fmaxf(s, 0.f);
    }
    __syncthreads();
    if (tid < 64) {
        float s = bfc2[0];
        for (int k = 0; k < 64; k++) s = fmaf(fc1[tid * 64 + k], Wfc2[k], s);
        out[tid] = s;
    }
}

extern "C" void kernel_launch(void* const* d_in, const int* in_sizes, int n_in,
                              void* d_out, int out_size, void* d_ws, size_t ws_size,
                              hipStream_t stream) {
    const float* x    = (const float*)d_in[0];
    const int*   edge = (const int*)d_in[1];
    const int*   batch= (const int*)d_in[2];
    const float* W1   = (const float*)d_in[3];
    const float* b1   = (const float*)d_in[4];
    const float* W2   = (const float*)d_in[5];
    const float* b2   = (const float*)d_in[6];
    const float* Wfc1 = (const float*)d_in[7];
    const float* bfc1 = (const float*)d_in[8];
    const float* Wfc2 = (const float*)d_in[9];
    const float* bfc2 = (const float*)d_in[10];
    float* out = (float*)d_out;

    int N = in_sizes[0] / 128;
    int E = in_sizes[1] / 2;
    const int* src = edge;
    const int* dst = edge + E;

    char* ws = (char*)d_ws;
    size_t off = 0;
    auto alloc = [&](size_t bytes) { void* p = ws + off; off += (bytes + 255) & ~(size_t)255; return p; };
    float* A      = (float*)alloc((size_t)N * 128 * sizeof(float));
    float* B      = (float*)alloc((size_t)N * 128 * sizeof(float));
    float* dinv   = (float*)alloc((size_t)N * sizeof(float));
    int*   count  = (int*)alloc((size_t)N * sizeof(int));
    int*   tmp    = (int*)alloc((size_t)N * sizeof(int));
    int*   rowptr = (int*)alloc((size_t)(N + 1) * sizeof(int));
    int*   cursor = (int*)alloc((size_t)N * sizeof(int));
    int*   esrc   = (int*)alloc((size_t)E * sizeof(int));
    int*   bsum   = (int*)alloc(256 * sizeof(int));
    int*   boff   = (int*)alloc(256 * sizeof(int));
    float* pooled = (float*)alloc(64 * 128 * sizeof(float));
    float* cnt    = (float*)alloc(64 * sizeof(float));

    int nb = (N + 255) / 256;

    hipMemsetAsync(count, 0, (size_t)N * sizeof(int), stream);
    hipMemsetAsync(pooled, 0, 64 * 128 * sizeof(float), stream);
    hipMemsetAsync(cnt, 0, 64 * sizeof(float), stream);

    // CSR build
    hist_kernel<<<(E + 255) / 256, 256, 0, stream>>>(dst, count, E);
    scan1_kernel<<<nb, 256, 0, stream>>>(count, tmp, bsum, N);
    scan2_kernel<<<1, 256, 0, stream>>>(bsum, boff, nb);
    finalize_kernel<<<(N + 256) / 256, 256, 0, stream>>>(count, tmp, boff, rowptr, cursor, dinv, N);
    reorder_kernel<<<(E + 255) / 256, 256, 0, stream>>>(src, dst, cursor, esrc, E);

    int gblocks = (N + 63) / 64;
    int ablocks = (N + 3) / 4;

    // Layer 1
    gemm128<false><<<gblocks, 256, 0, stream>>>(x, W1, A, N);
    gather_csr<<<ablocks, 256, 0, stream>>>(A, dinv, b1, rowptr, esrc, B, N);

    // Layer 2 (relu fused into GEMM input read)
    gemm128<true><<<gblocks, 256, 0, stream>>>(B, W2, A, N);
    gather_csr<<<ablocks, 256, 0, stream>>>(A, dinv, b2, rowptr, esrc, B, N);

    // Pool (relu fused) + head
    pool_kernel<<<(N + 127) / 128, 256, 0, stream>>>(B, batch, pooled, cnt, N);
    head_kernel<<<1, 256, 0, stream>>>(pooled, cnt, Wfc1, bfc1, Wfc2, bfc2, out);
}